// Round 2
// baseline (6101.212 us; speedup 1.0000x reference)
//
#include <hip/hip_runtime.h>

#define B_ 2
#define N_ 16384
#define K_ 2048
#define CBEV 256
#define HH 128
#define WW 128
#define CIN 288
#define COUT 128

// ---------------- FPS ----------------
#define FPS_T 1024
#define FPS_PPT 16  // N_/FPS_T

__global__ __launch_bounds__(FPS_T, 4) void fps_kernel(
    const float4* __restrict__ points, float4* __restrict__ keypts)
{
  const int b = blockIdx.x;
  const int t = threadIdx.x;
  const int lane = t & 63;
  const int wid = t >> 6;  // 0..15
  const float4* pts = points + (size_t)b * N_;
  float px[FPS_PPT], py[FPS_PPT], pz[FPS_PPT], dd[FPS_PPT];
  const int base = t * FPS_PPT;
#pragma unroll
  for (int j = 0; j < FPS_PPT; ++j) {
    float4 p = pts[base + j];
    px[j] = p.x; py[j] = p.y; pz[j] = p.z;
    dd[j] = 1e10f;
  }
  // double-buffered per-wave winners (one barrier per iteration)
  __shared__ float swv[2][16], swx[2][16], swy[2][16], swz[2][16];
  __shared__ int swi[2][16];

  float4 p0 = pts[0];
  float qx = p0.x, qy = p0.y, qz = p0.z;
  if (t == 0) keypts[(size_t)b * K_] = make_float4(qx, qy, qz, 0.f);

  for (int it = 1; it < K_; ++it) {
    float lv = -1.f; int li = 0x7fffffff;
    float lx = 0.f, ly = 0.f, lz = 0.f;
#pragma unroll
    for (int j = 0; j < FPS_PPT; ++j) {
      // EXACT reference arithmetic: no FMA contraction, ((dx*dx+dy*dy)+dz*dz)
      float dx = __fsub_rn(px[j], qx);
      float dy = __fsub_rn(py[j], qy);
      float dz = __fsub_rn(pz[j], qz);
      float d = __fadd_rn(__fadd_rn(__fmul_rn(dx, dx), __fmul_rn(dy, dy)),
                          __fmul_rn(dz, dz));
      d = fminf(dd[j], d);
      dd[j] = d;
      if (d > lv) { lv = d; li = base + j; lx = px[j]; ly = py[j]; lz = pz[j]; }
    }
    // wave butterfly argmax reduce, tie -> smaller index (numpy first-occurrence)
#pragma unroll
    for (int off = 32; off > 0; off >>= 1) {
      float ov = __shfl_xor(lv, off);
      int oi = __shfl_xor(li, off);
      float ox = __shfl_xor(lx, off);
      float oy = __shfl_xor(ly, off);
      float oz = __shfl_xor(lz, off);
      if (ov > lv || (ov == lv && oi < li)) { lv = ov; li = oi; lx = ox; ly = oy; lz = oz; }
    }
    const int pr = it & 1;
    if (lane == 0) {
      swv[pr][wid] = lv; swi[pr][wid] = li;
      swx[pr][wid] = lx; swy[pr][wid] = ly; swz[pr][wid] = lz;
    }
    __syncthreads();
    // every thread redundantly reduces the 16 wave winners -> no 2nd barrier
    {
      const int s = lane & 15;
      float v = swv[pr][s]; int i2 = swi[pr][s];
      float xx = swx[pr][s], yy = swy[pr][s], zz = swz[pr][s];
#pragma unroll
      for (int off = 8; off > 0; off >>= 1) {
        float ov = __shfl_xor(v, off);
        int oi = __shfl_xor(i2, off);
        float ox = __shfl_xor(xx, off);
        float oy = __shfl_xor(yy, off);
        float oz = __shfl_xor(zz, off);
        if (ov > v || (ov == v && oi < i2)) { v = ov; i2 = oi; xx = ox; yy = oy; zz = oz; }
      }
      qx = xx; qy = yy; qz = zz;
      if (t == 0) keypts[(size_t)b * K_ + it] = make_float4(xx, yy, zz, 0.f);
    }
  }
}

// ---------------- bilinear BEV sampling ----------------
__global__ __launch_bounds__(256) void bilinear_kernel(
    const float* __restrict__ bev, const float4* __restrict__ keypts,
    float* __restrict__ feat)
{
  const int kb = blockIdx.x;      // 0..B*K-1
  const int b = kb >> 11;         // / K_
  const int c = threadIdx.x;      // channel
  float4 kp = keypts[kb];
  // exact reference op order: (x - (-51.2)) / 0.1 / 8.0 in f32 RN
  float x = __fsub_rn(kp.x, -51.2f); x = x / 0.1f; x = x / 8.0f;
  float y = __fsub_rn(kp.y, -51.2f); y = y / 0.1f; y = y / 8.0f;
  int xf = (int)floorf(x);
  int yf = (int)floorf(y);
  int x0 = min(max(xf, 0), WW - 1);
  int x1 = min(max(xf + 1, 0), WW - 1);
  int y0 = min(max(yf, 0), HH - 1);
  int y1 = min(max(yf + 1, 0), HH - 1);
  float x0f = (float)x0, x1f = (float)x1, y0f = (float)y0, y1f = (float)y1;
  float wa = (x1f - x) * (y1f - y);
  float wb = (x1f - x) * (y - y0f);
  float wc = (x - x0f) * (y1f - y);
  float wd = (x - x0f) * (y - y0f);
  const float* bb = bev + ((size_t)b * CBEV + c) * (HH * WW);
  float Ia = bb[y0 * WW + x0];
  float Ib = bb[y1 * WW + x0];
  float Ic = bb[y0 * WW + x1];
  float Id = bb[y1 * WW + x1];
  float v = Ia * wa + Ib * wb + Ic * wc + Id * wd;
  feat[(size_t)kb * CIN + c] = v;
}

// ---------------- grouping + 2x tiny MLP + maxpool ----------------
__global__ __launch_bounds__(256) void group_kernel(
    const float4* __restrict__ points, const float4* __restrict__ keypts,
    const float* __restrict__ sa_w1, const float* __restrict__ sa_s1,
    const float* __restrict__ sa_b1, const float* __restrict__ sa_w2,
    const float* __restrict__ sa_s2, const float* __restrict__ sa_b2,
    float* __restrict__ feat)
{
  const int w = threadIdx.x >> 6;      // wave id 0..3
  const int lane = threadIdx.x & 63;
  const int kb = blockIdx.x * 4 + w;   // keypoint id
  const int b = kb >> 11;
  const int d = lane & 15;
  __shared__ int l1[4][16];
  __shared__ int l2[4][32];
  const float4* pts = points + (size_t)b * N_;
  float4 kp = keypts[kb];
  const float r2a = (float)(0.4 * 0.4);
  const float r2b = (float)(0.8 * 0.8);
  int c1 = 0, c2 = 0;
  for (int base = 0; base < N_; base += 64) {
    float4 p = pts[base + lane];
    float dx = __fsub_rn(kp.x, p.x);
    float dy = __fsub_rn(kp.y, p.y);
    float dz = __fsub_rn(kp.z, p.z);
    float d2 = __fadd_rn(__fadd_rn(__fmul_rn(dx, dx), __fmul_rn(dy, dy)),
                         __fmul_rn(dz, dz));
    unsigned long long m2 = __ballot(d2 < r2b);
    unsigned long long m1 = __ballot(d2 < r2a);
    unsigned long long below = (lane == 0) ? 0ull : ((~0ull) >> (64 - lane));
    if (c2 < 32 && m2) {
      int pos = c2 + __popcll(m2 & below);
      if (((m2 >> lane) & 1ull) && pos < 32) l2[w][pos] = base + lane;
      c2 += __popcll(m2); if (c2 > 32) c2 = 32;
    }
    if (c1 < 16 && m1) {
      int pos = c1 + __popcll(m1 & below);
      if (((m1 >> lane) & 1ull) && pos < 16) l1[w][pos] = base + lane;
      c1 += __popcll(m1); if (c1 > 16) c1 = 16;
    }
    if (c1 >= 16 && c2 >= 32) break;
  }
  __syncthreads();

  float pooled[2];
#pragma unroll
  for (int br = 0; br < 2; ++br) {
    const int wo1 = br * 64, so1 = br * 16, wo2 = br * 256;
    float w1r[4], w2r[16];
#pragma unroll
    for (int c = 0; c < 4; ++c) w1r[c] = sa_w1[wo1 + c * 16 + d];
#pragma unroll
    for (int c = 0; c < 16; ++c) w2r[c] = sa_w2[wo2 + c * 16 + d];
    float s1d = sa_s1[so1 + d], b1d = sa_b1[so1 + d];
    float s2d = sa_s2[so1 + d], b2d = sa_b2[so1 + d];
    int cnt = (br == 0) ? c1 : c2;
    float vm = -1e30f;
    int n = cnt > 0 ? cnt : 1;
    for (int j = 0; j < n; ++j) {
      float g0 = 0.f, g1 = 0.f, g2 = 0.f, g3 = 0.f;
      if (j < cnt) {
        int pi = (br == 0) ? l1[w][j] : l2[w][j];
        float4 p = pts[pi];
        g0 = p.x - kp.x; g1 = p.y - kp.y; g2 = p.z - kp.z; g3 = p.w;
      }
      float a = g0 * w1r[0] + g1 * w1r[1] + g2 * w1r[2] + g3 * w1r[3];
      float h1 = fmaxf(0.f, fmaf(a, s1d, b1d));
      float a2 = 0.f;
#pragma unroll
      for (int c = 0; c < 16; ++c) a2 = fmaf(__shfl(h1, c), w2r[c], a2);
      float h2 = fmaxf(0.f, fmaf(a2, s2d, b2d));
      vm = fmaxf(vm, h2);
    }
    pooled[br] = vm;
  }
  if (lane < 16) {
    feat[(size_t)kb * CIN + 256 + d] = pooled[0];
    feat[(size_t)kb * CIN + 272 + d] = pooled[1];
  }
}

// ---------------- fused linear + relu ----------------
__global__ __launch_bounds__(128) void fuse_kernel(
    const float* __restrict__ feat, const float* __restrict__ fw,
    const float* __restrict__ fs, const float* __restrict__ fb,
    float* __restrict__ out)
{
  __shared__ float rows[8 * CIN];
  const int d = threadIdx.x;
  const size_t r0 = (size_t)blockIdx.x * 8;
  for (int i = d; i < 8 * CIN; i += 128) rows[i] = feat[r0 * CIN + i];
  __syncthreads();
  float acc[8];
#pragma unroll
  for (int r = 0; r < 8; ++r) acc[r] = 0.f;
  for (int c = 0; c < CIN; ++c) {
    float wv = fw[c * COUT + d];
#pragma unroll
    for (int r = 0; r < 8; ++r) acc[r] = fmaf(rows[r * CIN + c], wv, acc[r]);
  }
  float sd = fs[d], bd = fb[d];
#pragma unroll
  for (int r = 0; r < 8; ++r)
    out[(r0 + r) * COUT + d] = fmaxf(0.f, fmaf(acc[r], sd, bd));
}

extern "C" void kernel_launch(void* const* d_in, const int* in_sizes, int n_in,
                              void* d_out, int out_size, void* d_ws, size_t ws_size,
                              hipStream_t stream) {
  const float4* points = (const float4*)d_in[0];
  const float* bev    = (const float*)d_in[1];
  const float* sa_w1  = (const float*)d_in[2];
  const float* sa_s1  = (const float*)d_in[3];
  const float* sa_b1  = (const float*)d_in[4];
  const float* sa_w2  = (const float*)d_in[5];
  const float* sa_s2  = (const float*)d_in[6];
  const float* sa_b2  = (const float*)d_in[7];
  const float* fuse_w = (const float*)d_in[8];
  const float* fuse_s = (const float*)d_in[9];
  const float* fuse_b = (const float*)d_in[10];
  float* out = (float*)d_out;

  float* feat = (float*)d_ws;                                // 4096*288 f32
  float4* keypts = (float4*)((char*)d_ws + (size_t)(B_ * K_) * CIN * sizeof(float));

  hipLaunchKernelGGL(fps_kernel, dim3(B_), dim3(FPS_T), 0, stream, points, keypts);
  hipLaunchKernelGGL(bilinear_kernel, dim3(B_ * K_), dim3(256), 0, stream,
                     bev, keypts, feat);
  hipLaunchKernelGGL(group_kernel, dim3(B_ * K_ / 4), dim3(256), 0, stream,
                     points, keypts, sa_w1, sa_s1, sa_b1, sa_w2, sa_s2, sa_b2, feat);
  hipLaunchKernelGGL(fuse_kernel, dim3(B_ * K_ / 8), dim3(128), 0, stream,
                     feat, fuse_w, fuse_s, fuse_b, out);
}

// Round 3
// 3881.634 us; speedup vs baseline: 1.5718x; 1.5718x over previous
//
#include <hip/hip_runtime.h>

#define B_ 2
#define N_ 16384
#define K_ 2048
#define CBEV 256
#define HH 128
#define WW 128
#define CIN 288
#define COUT 128

typedef float f32x2 __attribute__((ext_vector_type(2)));

// ---------------- FPS ----------------
#define FPS_T 1024
#define FPS_PAIRS 8  // 16 points/thread = 8 float2 pairs

__global__ __launch_bounds__(FPS_T) void fps_kernel(
    const float4* __restrict__ points, float4* __restrict__ keypts)
{
  const int b = blockIdx.x;
  const int t = threadIdx.x;
  const int lane = t & 63;
  const int wid = t >> 6;  // 0..15
  const float4* pts = points + (size_t)b * N_;
  f32x2 px[FPS_PAIRS], py[FPS_PAIRS], pz[FPS_PAIRS], dd[FPS_PAIRS];
  const int base = t * (FPS_PAIRS * 2);
#pragma unroll
  for (int j = 0; j < FPS_PAIRS; ++j) {
    float4 p0 = pts[base + 2 * j];
    float4 p1 = pts[base + 2 * j + 1];
    px[j].x = p0.x; px[j].y = p1.x;
    py[j].x = p0.y; py[j].y = p1.y;
    pz[j].x = p0.z; pz[j].y = p1.z;
    dd[j].x = 1e10f; dd[j].y = 1e10f;
  }
  __shared__ unsigned long long skey[2][16];

  float4 q = pts[0];
  if (t == 0) keypts[(size_t)b * K_] = q;

  for (int it = 1; it < K_; ++it) {
#pragma clang fp contract(off)
    f32x2 qx, qy, qz;
    qx.x = q.x; qx.y = q.x;
    qy.x = q.y; qy.y = q.y;
    qz.x = q.z; qz.y = q.z;
    float lv0 = -1.f, lv1 = -1.f;
    int lj0 = 0, lj1 = 0;
#pragma unroll
    for (int j = 0; j < FPS_PAIRS; ++j) {
      // EXACT reference arithmetic: RN sub/mul/add, ((dx^2+dy^2)+dz^2),
      // contraction disabled -> v_pk_mul/add, bit-identical to scalar RN.
      f32x2 dx = px[j] - qx;
      f32x2 dy = py[j] - qy;
      f32x2 dz = pz[j] - qz;
      f32x2 d = dx * dx + dy * dy + dz * dz;
      d = __builtin_elementwise_min(dd[j], d);
      dd[j] = d;
      if (d.x > lv0) { lv0 = d.x; lj0 = base + 2 * j; }
      if (d.y > lv1) { lv1 = d.y; lj1 = base + 2 * j + 1; }
    }
    // merge the two chains; exact tie -> smaller global index
    float lv; int lj;
    if (lv1 > lv0 || (lv1 == lv0 && lj1 < lj0)) { lv = lv1; lj = lj1; }
    else { lv = lv0; lj = lj0; }
    // pack (dist, idx) into sortable u64: d >= 0 so f32 bits are monotone;
    // low word 0x3FFF-idx makes umax tie-break to the SMALLEST index.
    unsigned long long k =
        (((unsigned long long)__float_as_uint(lv)) << 32) |
        (unsigned int)(0x3FFF - lj);
#pragma unroll
    for (int off = 32; off > 0; off >>= 1) {
      unsigned long long ok = __shfl_xor(k, off);
      if (ok > k) k = ok;
    }
    const int pr = it & 1;
    if (lane == 0) skey[pr][wid] = k;
    __syncthreads();  // single barrier; double-buffered slots avoid WAR race
    k = skey[pr][lane & 15];
#pragma unroll
    for (int off = 8; off > 0; off >>= 1) {
      unsigned long long ok = __shfl_xor(k, off);
      if (ok > k) k = ok;
    }
    int g = 0x3FFF - (int)(unsigned int)(k & 0xFFFFFFFFull);
    g = __builtin_amdgcn_readfirstlane(g);
    q = pts[g];  // uniform broadcast re-fetch of winner coords
    if (t == 0) keypts[(size_t)b * K_ + it] = q;
  }
}

// ---------------- bilinear BEV sampling ----------------
__global__ __launch_bounds__(256) void bilinear_kernel(
    const float* __restrict__ bev, const float4* __restrict__ keypts,
    float* __restrict__ feat)
{
  const int kb = blockIdx.x;      // 0..B*K-1
  const int b = kb >> 11;         // / K_
  const int c = threadIdx.x;      // channel
  float4 kp = keypts[kb];
  // exact reference op order: (x - (-51.2)) / 0.1 / 8.0 in f32 RN
  float x = __fsub_rn(kp.x, -51.2f); x = x / 0.1f; x = x / 8.0f;
  float y = __fsub_rn(kp.y, -51.2f); y = y / 0.1f; y = y / 8.0f;
  int xf = (int)floorf(x);
  int yf = (int)floorf(y);
  int x0 = min(max(xf, 0), WW - 1);
  int x1 = min(max(xf + 1, 0), WW - 1);
  int y0 = min(max(yf, 0), HH - 1);
  int y1 = min(max(yf + 1, 0), HH - 1);
  float x0f = (float)x0, x1f = (float)x1, y0f = (float)y0, y1f = (float)y1;
  float wa = (x1f - x) * (y1f - y);
  float wb = (x1f - x) * (y - y0f);
  float wc = (x - x0f) * (y1f - y);
  float wd = (x - x0f) * (y - y0f);
  const float* bb = bev + ((size_t)b * CBEV + c) * (HH * WW);
  float Ia = bb[y0 * WW + x0];
  float Ib = bb[y1 * WW + x0];
  float Ic = bb[y0 * WW + x1];
  float Id = bb[y1 * WW + x1];
  float v = Ia * wa + Ib * wb + Ic * wc + Id * wd;
  feat[(size_t)kb * CIN + c] = v;
}

// ---------------- grouping + 2x tiny MLP + maxpool ----------------
__global__ __launch_bounds__(256) void group_kernel(
    const float4* __restrict__ points, const float4* __restrict__ keypts,
    const float* __restrict__ sa_w1, const float* __restrict__ sa_s1,
    const float* __restrict__ sa_b1, const float* __restrict__ sa_w2,
    const float* __restrict__ sa_s2, const float* __restrict__ sa_b2,
    float* __restrict__ feat)
{
  const int w = threadIdx.x >> 6;      // wave id 0..3
  const int lane = threadIdx.x & 63;
  const int kb = blockIdx.x * 4 + w;   // keypoint id
  const int b = kb >> 11;
  const int d = lane & 15;
  __shared__ int l1[4][16];
  __shared__ int l2[4][32];
  const float4* pts = points + (size_t)b * N_;
  float4 kp = keypts[kb];
  const float r2a = (float)(0.4 * 0.4);
  const float r2b = (float)(0.8 * 0.8);
  int c1 = 0, c2 = 0;
  for (int base = 0; base < N_; base += 64) {
    float4 p = pts[base + lane];
    float dx = __fsub_rn(kp.x, p.x);
    float dy = __fsub_rn(kp.y, p.y);
    float dz = __fsub_rn(kp.z, p.z);
    float d2 = __fadd_rn(__fadd_rn(__fmul_rn(dx, dx), __fmul_rn(dy, dy)),
                         __fmul_rn(dz, dz));
    unsigned long long m2 = __ballot(d2 < r2b);
    unsigned long long m1 = __ballot(d2 < r2a);
    unsigned long long below = (lane == 0) ? 0ull : ((~0ull) >> (64 - lane));
    if (c2 < 32 && m2) {
      int pos = c2 + __popcll(m2 & below);
      if (((m2 >> lane) & 1ull) && pos < 32) l2[w][pos] = base + lane;
      c2 += __popcll(m2); if (c2 > 32) c2 = 32;
    }
    if (c1 < 16 && m1) {
      int pos = c1 + __popcll(m1 & below);
      if (((m1 >> lane) & 1ull) && pos < 16) l1[w][pos] = base + lane;
      c1 += __popcll(m1); if (c1 > 16) c1 = 16;
    }
    if (c1 >= 16 && c2 >= 32) break;
  }
  __syncthreads();

  float pooled[2];
#pragma unroll
  for (int br = 0; br < 2; ++br) {
    const int wo1 = br * 64, so1 = br * 16, wo2 = br * 256;
    float w1r[4], w2r[16];
#pragma unroll
    for (int c = 0; c < 4; ++c) w1r[c] = sa_w1[wo1 + c * 16 + d];
#pragma unroll
    for (int c = 0; c < 16; ++c) w2r[c] = sa_w2[wo2 + c * 16 + d];
    float s1d = sa_s1[so1 + d], b1d = sa_b1[so1 + d];
    float s2d = sa_s2[so1 + d], b2d = sa_b2[so1 + d];
    int cnt = (br == 0) ? c1 : c2;
    float vm = -1e30f;
    int n = cnt > 0 ? cnt : 1;
    for (int j = 0; j < n; ++j) {
      float g0 = 0.f, g1 = 0.f, g2 = 0.f, g3 = 0.f;
      if (j < cnt) {
        int pi = (br == 0) ? l1[w][j] : l2[w][j];
        float4 p = pts[pi];
        g0 = p.x - kp.x; g1 = p.y - kp.y; g2 = p.z - kp.z; g3 = p.w;
      }
      float a = g0 * w1r[0] + g1 * w1r[1] + g2 * w1r[2] + g3 * w1r[3];
      float h1 = fmaxf(0.f, fmaf(a, s1d, b1d));
      float a2 = 0.f;
#pragma unroll
      for (int c = 0; c < 16; ++c) a2 = fmaf(__shfl(h1, c), w2r[c], a2);
      float h2 = fmaxf(0.f, fmaf(a2, s2d, b2d));
      vm = fmaxf(vm, h2);
    }
    pooled[br] = vm;
  }
  if (lane < 16) {
    feat[(size_t)kb * CIN + 256 + d] = pooled[0];
    feat[(size_t)kb * CIN + 272 + d] = pooled[1];
  }
}

// ---------------- fused linear + relu ----------------
__global__ __launch_bounds__(128) void fuse_kernel(
    const float* __restrict__ feat, const float* __restrict__ fw,
    const float* __restrict__ fs, const float* __restrict__ fb,
    float* __restrict__ out)
{
  __shared__ float rows[8 * CIN];
  const int d = threadIdx.x;
  const size_t r0 = (size_t)blockIdx.x * 8;
  for (int i = d; i < 8 * CIN; i += 128) rows[i] = feat[r0 * CIN + i];
  __syncthreads();
  float acc[8];
#pragma unroll
  for (int r = 0; r < 8; ++r) acc[r] = 0.f;
  for (int c = 0; c < CIN; ++c) {
    float wv = fw[c * COUT + d];
#pragma unroll
    for (int r = 0; r < 8; ++r) acc[r] = fmaf(rows[r * CIN + c], wv, acc[r]);
  }
  float sd = fs[d], bd = fb[d];
#pragma unroll
  for (int r = 0; r < 8; ++r)
    out[(r0 + r) * COUT + d] = fmaxf(0.f, fmaf(acc[r], sd, bd));
}

extern "C" void kernel_launch(void* const* d_in, const int* in_sizes, int n_in,
                              void* d_out, int out_size, void* d_ws, size_t ws_size,
                              hipStream_t stream) {
  const float4* points = (const float4*)d_in[0];
  const float* bev    = (const float*)d_in[1];
  const float* sa_w1  = (const float*)d_in[2];
  const float* sa_s1  = (const float*)d_in[3];
  const float* sa_b1  = (const float*)d_in[4];
  const float* sa_w2  = (const float*)d_in[5];
  const float* sa_s2  = (const float*)d_in[6];
  const float* sa_b2  = (const float*)d_in[7];
  const float* fuse_w = (const float*)d_in[8];
  const float* fuse_s = (const float*)d_in[9];
  const float* fuse_b = (const float*)d_in[10];
  float* out = (float*)d_out;

  float* feat = (float*)d_ws;                                // 4096*288 f32
  float4* keypts = (float4*)((char*)d_ws + (size_t)(B_ * K_) * CIN * sizeof(float));

  hipLaunchKernelGGL(fps_kernel, dim3(B_), dim3(FPS_T), 0, stream, points, keypts);
  hipLaunchKernelGGL(bilinear_kernel, dim3(B_ * K_), dim3(256), 0, stream,
                     bev, keypts, feat);
  hipLaunchKernelGGL(group_kernel, dim3(B_ * K_ / 4), dim3(256), 0, stream,
                     points, keypts, sa_w1, sa_s1, sa_b1, sa_w2, sa_s2, sa_b2, feat);
  hipLaunchKernelGGL(fuse_kernel, dim3(B_ * K_ / 8), dim3(128), 0, stream,
                     feat, fuse_w, fuse_s, fuse_b, out);
}

// Round 4
// 3441.621 us; speedup vs baseline: 1.7728x; 1.1279x over previous
//
#include <hip/hip_runtime.h>

#define B_ 2
#define N_ 16384
#define K_ 2048
#define CBEV 256
#define HH 128
#define WW 128
#define CIN 288
#define COUT 128

typedef float f32x2 __attribute__((ext_vector_type(2)));

// ---------------- FPS ----------------
#define FPS_T 512
#define FPS_PAIRS 16  // 32 points/thread = 16 float2 pairs

// waves_per_eu(2,2): pin allocator to exactly 2 waves/SIMD -> 256-VGPR budget.
// Point data (px,py,pz,dd as f32x2[16]) = 128 VGPRs + ~30 working: spill-free.
__global__ __launch_bounds__(FPS_T)
__attribute__((amdgpu_waves_per_eu(2, 2))) void fps_kernel(
    const float4* __restrict__ points, float4* __restrict__ keypts)
{
  const int b = blockIdx.x;
  const int t = threadIdx.x;
  const int lane = t & 63;
  const int wid = t >> 6;  // 0..7
  const float4* pts = points + (size_t)b * N_;
  f32x2 px[FPS_PAIRS], py[FPS_PAIRS], pz[FPS_PAIRS], dd[FPS_PAIRS];
  const int base = t * (FPS_PAIRS * 2);
#pragma unroll
  for (int j = 0; j < FPS_PAIRS; ++j) {
    float4 p0 = pts[base + 2 * j];
    float4 p1 = pts[base + 2 * j + 1];
    px[j].x = p0.x; px[j].y = p1.x;
    py[j].x = p0.y; py[j].y = p1.y;
    pz[j].x = p0.z; pz[j].y = p1.z;
    dd[j].x = 1e10f; dd[j].y = 1e10f;
  }
  __shared__ unsigned long long skey[2][8];

  float4 q = pts[0];
  if (t == 0) keypts[(size_t)b * K_] = q;

  for (int it = 1; it < K_; ++it) {
#pragma clang fp contract(off)
    f32x2 qx, qy, qz;
    qx.x = q.x; qx.y = q.x;
    qy.x = q.y; qy.y = q.y;
    qz.x = q.z; qz.y = q.z;
    float lv0 = -1.f, lv1 = -1.f;
    int lj0 = 0, lj1 = 0;
#pragma unroll
    for (int j = 0; j < FPS_PAIRS; ++j) {
      // EXACT reference arithmetic: RN sub/mul/add, ((dx^2+dy^2)+dz^2),
      // contraction disabled -> v_pk_mul/add, bit-identical to scalar RN.
      f32x2 dx = px[j] - qx;
      f32x2 dy = py[j] - qy;
      f32x2 dz = pz[j] - qz;
      f32x2 d = dx * dx + dy * dy + dz * dz;
      d = __builtin_elementwise_min(dd[j], d);
      dd[j] = d;
      if (d.x > lv0) { lv0 = d.x; lj0 = base + 2 * j; }
      if (d.y > lv1) { lv1 = d.y; lj1 = base + 2 * j + 1; }
    }
    // merge the two chains; exact tie -> smaller global index
    float lv; int lj;
    if (lv1 > lv0 || (lv1 == lv0 && lj1 < lj0)) { lv = lv1; lj = lj1; }
    else { lv = lv0; lj = lj0; }
    // pack (dist, idx) into sortable u64: d >= 0 so f32 bits are monotone;
    // low word 0x3FFF-idx makes umax tie-break to the SMALLEST index.
    unsigned long long k =
        (((unsigned long long)__float_as_uint(lv)) << 32) |
        (unsigned int)(0x3FFF - lj);
#pragma unroll
    for (int off = 32; off > 0; off >>= 1) {
      unsigned long long ok = __shfl_xor(k, off);
      if (ok > k) k = ok;
    }
    const int pr = it & 1;
    if (lane == 0) skey[pr][wid] = k;
    __syncthreads();  // single barrier; double-buffered slots avoid WAR race
    k = skey[pr][lane & 7];
#pragma unroll
    for (int off = 4; off > 0; off >>= 1) {
      unsigned long long ok = __shfl_xor(k, off);
      if (ok > k) k = ok;
    }
    int g = 0x3FFF - (int)(unsigned int)(k & 0xFFFFFFFFull);
    g = __builtin_amdgcn_readfirstlane(g);
    q = pts[g];  // uniform broadcast re-fetch of winner coords
    if (t == 0) keypts[(size_t)b * K_ + it] = q;
  }
}

// ---------------- bilinear BEV sampling ----------------
__global__ __launch_bounds__(256) void bilinear_kernel(
    const float* __restrict__ bev, const float4* __restrict__ keypts,
    float* __restrict__ feat)
{
  const int kb = blockIdx.x;      // 0..B*K-1
  const int b = kb >> 11;         // / K_
  const int c = threadIdx.x;      // channel
  float4 kp = keypts[kb];
  // exact reference op order: (x - (-51.2)) / 0.1 / 8.0 in f32 RN
  float x = __fsub_rn(kp.x, -51.2f); x = x / 0.1f; x = x / 8.0f;
  float y = __fsub_rn(kp.y, -51.2f); y = y / 0.1f; y = y / 8.0f;
  int xf = (int)floorf(x);
  int yf = (int)floorf(y);
  int x0 = min(max(xf, 0), WW - 1);
  int x1 = min(max(xf + 1, 0), WW - 1);
  int y0 = min(max(yf, 0), HH - 1);
  int y1 = min(max(yf + 1, 0), HH - 1);
  float x0f = (float)x0, x1f = (float)x1, y0f = (float)y0, y1f = (float)y1;
  float wa = (x1f - x) * (y1f - y);
  float wb = (x1f - x) * (y - y0f);
  float wc = (x - x0f) * (y1f - y);
  float wd = (x - x0f) * (y - y0f);
  const float* bb = bev + ((size_t)b * CBEV + c) * (HH * WW);
  float Ia = bb[y0 * WW + x0];
  float Ib = bb[y1 * WW + x0];
  float Ic = bb[y0 * WW + x1];
  float Id = bb[y1 * WW + x1];
  float v = Ia * wa + Ib * wb + Ic * wc + Id * wd;
  feat[(size_t)kb * CIN + c] = v;
}

// ---------------- grouping + 2x tiny MLP + maxpool ----------------
__global__ __launch_bounds__(256) void group_kernel(
    const float4* __restrict__ points, const float4* __restrict__ keypts,
    const float* __restrict__ sa_w1, const float* __restrict__ sa_s1,
    const float* __restrict__ sa_b1, const float* __restrict__ sa_w2,
    const float* __restrict__ sa_s2, const float* __restrict__ sa_b2,
    float* __restrict__ feat)
{
  const int w = threadIdx.x >> 6;      // wave id 0..3
  const int lane = threadIdx.x & 63;
  const int kb = blockIdx.x * 4 + w;   // keypoint id
  const int b = kb >> 11;
  const int d = lane & 15;
  __shared__ int l1[4][16];
  __shared__ int l2[4][32];
  const float4* pts = points + (size_t)b * N_;
  float4 kp = keypts[kb];
  const float r2a = (float)(0.4 * 0.4);
  const float r2b = (float)(0.8 * 0.8);
  int c1 = 0, c2 = 0;
  for (int base = 0; base < N_; base += 64) {
    float4 p = pts[base + lane];
    float dx = __fsub_rn(kp.x, p.x);
    float dy = __fsub_rn(kp.y, p.y);
    float dz = __fsub_rn(kp.z, p.z);
    float d2 = __fadd_rn(__fadd_rn(__fmul_rn(dx, dx), __fmul_rn(dy, dy)),
                         __fmul_rn(dz, dz));
    unsigned long long m2 = __ballot(d2 < r2b);
    unsigned long long m1 = __ballot(d2 < r2a);
    unsigned long long below = (lane == 0) ? 0ull : ((~0ull) >> (64 - lane));
    if (c2 < 32 && m2) {
      int pos = c2 + __popcll(m2 & below);
      if (((m2 >> lane) & 1ull) && pos < 32) l2[w][pos] = base + lane;
      c2 += __popcll(m2); if (c2 > 32) c2 = 32;
    }
    if (c1 < 16 && m1) {
      int pos = c1 + __popcll(m1 & below);
      if (((m1 >> lane) & 1ull) && pos < 16) l1[w][pos] = base + lane;
      c1 += __popcll(m1); if (c1 > 16) c1 = 16;
    }
    if (c1 >= 16 && c2 >= 32) break;
  }
  __syncthreads();

  float pooled[2];
#pragma unroll
  for (int br = 0; br < 2; ++br) {
    const int wo1 = br * 64, so1 = br * 16, wo2 = br * 256;
    float w1r[4], w2r[16];
#pragma unroll
    for (int c = 0; c < 4; ++c) w1r[c] = sa_w1[wo1 + c * 16 + d];
#pragma unroll
    for (int c = 0; c < 16; ++c) w2r[c] = sa_w2[wo2 + c * 16 + d];
    float s1d = sa_s1[so1 + d], b1d = sa_b1[so1 + d];
    float s2d = sa_s2[so1 + d], b2d = sa_b2[so1 + d];
    int cnt = (br == 0) ? c1 : c2;
    float vm = -1e30f;
    int n = cnt > 0 ? cnt : 1;
    for (int j = 0; j < n; ++j) {
      float g0 = 0.f, g1 = 0.f, g2 = 0.f, g3 = 0.f;
      if (j < cnt) {
        int pi = (br == 0) ? l1[w][j] : l2[w][j];
        float4 p = pts[pi];
        g0 = p.x - kp.x; g1 = p.y - kp.y; g2 = p.z - kp.z; g3 = p.w;
      }
      float a = g0 * w1r[0] + g1 * w1r[1] + g2 * w1r[2] + g3 * w1r[3];
      float h1 = fmaxf(0.f, fmaf(a, s1d, b1d));
      float a2 = 0.f;
#pragma unroll
      for (int c = 0; c < 16; ++c) a2 = fmaf(__shfl(h1, c), w2r[c], a2);
      float h2 = fmaxf(0.f, fmaf(a2, s2d, b2d));
      vm = fmaxf(vm, h2);
    }
    pooled[br] = vm;
  }
  if (lane < 16) {
    feat[(size_t)kb * CIN + 256 + d] = pooled[0];
    feat[(size_t)kb * CIN + 272 + d] = pooled[1];
  }
}

// ---------------- fused linear + relu ----------------
__global__ __launch_bounds__(128) void fuse_kernel(
    const float* __restrict__ feat, const float* __restrict__ fw,
    const float* __restrict__ fs, const float* __restrict__ fb,
    float* __restrict__ out)
{
  __shared__ float rows[8 * CIN];
  const int d = threadIdx.x;
  const size_t r0 = (size_t)blockIdx.x * 8;
  for (int i = d; i < 8 * CIN; i += 128) rows[i] = feat[r0 * CIN + i];
  __syncthreads();
  float acc[8];
#pragma unroll
  for (int r = 0; r < 8; ++r) acc[r] = 0.f;
  for (int c = 0; c < CIN; ++c) {
    float wv = fw[c * COUT + d];
#pragma unroll
    for (int r = 0; r < 8; ++r) acc[r] = fmaf(rows[r * CIN + c], wv, acc[r]);
  }
  float sd = fs[d], bd = fb[d];
#pragma unroll
  for (int r = 0; r < 8; ++r)
    out[(r0 + r) * COUT + d] = fmaxf(0.f, fmaf(acc[r], sd, bd));
}

extern "C" void kernel_launch(void* const* d_in, const int* in_sizes, int n_in,
                              void* d_out, int out_size, void* d_ws, size_t ws_size,
                              hipStream_t stream) {
  const float4* points = (const float4*)d_in[0];
  const float* bev    = (const float*)d_in[1];
  const float* sa_w1  = (const float*)d_in[2];
  const float* sa_s1  = (const float*)d_in[3];
  const float* sa_b1  = (const float*)d_in[4];
  const float* sa_w2  = (const float*)d_in[5];
  const float* sa_s2  = (const float*)d_in[6];
  const float* sa_b2  = (const float*)d_in[7];
  const float* fuse_w = (const float*)d_in[8];
  const float* fuse_s = (const float*)d_in[9];
  const float* fuse_b = (const float*)d_in[10];
  float* out = (float*)d_out;

  float* feat = (float*)d_ws;                                // 4096*288 f32
  float4* keypts = (float4*)((char*)d_ws + (size_t)(B_ * K_) * CIN * sizeof(float));

  hipLaunchKernelGGL(fps_kernel, dim3(B_), dim3(FPS_T), 0, stream, points, keypts);
  hipLaunchKernelGGL(bilinear_kernel, dim3(B_ * K_), dim3(256), 0, stream,
                     bev, keypts, feat);
  hipLaunchKernelGGL(group_kernel, dim3(B_ * K_ / 4), dim3(256), 0, stream,
                     points, keypts, sa_w1, sa_s1, sa_b1, sa_w2, sa_s2, sa_b2, feat);
  hipLaunchKernelGGL(fuse_kernel, dim3(B_ * K_ / 8), dim3(128), 0, stream,
                     feat, fuse_w, fuse_s, fuse_b, out);
}